// Round 9
// baseline (21.481 us; speedup 1.0000x reference)
//
#include <hip/hip_runtime.h>

// YOLOv3 loss on MI355X — round 9: block-count cut at constant wave count.
// Hypothesis: ~4ns/block dispatch ramp => 1267 blocks ~ 5us. Now 468 blocks:
//   blocks [0,300):   correct — 8 waves/block, one wave per (scale,b,t);
//                     in-register build; cell loads issued BEFORE canon ballot;
//                     single-writer fast path for class union.
//   blocks [300,467): noobj — 512 threads x 2 independent cells each.
// final kernel: 1 block x 512 threads reduces compact slot tables.

#define NB 16      // batch
#define NT 50      // targets per batch
#define NA 3       // anchors
#define NC 80      // classes
#define NCORR 300  // correct blocks (300*8 waves = 2400 = 3*16*50)
#define NNB 167    // noobj blocks (167*1024 cells >= 170352)
#define NBLK 467

__device__ __forceinline__ float bce0(float p) { return -log1pf(-p); } // target 0
__device__ __forceinline__ float bce1(float p) { return -logf(p); }    // target 1

// scorr row j: scale*9 + {0..3 mse, 4 obj, 5 noobj_corr, 6 cls, 7 n_pos, 8 n_zeroed}
__global__ __launch_bounds__(512) void main_kernel(
    const float* __restrict__ o13,
    const float* __restrict__ o26,
    const float* __restrict__ o52,
    const float* __restrict__ targets,
    const float* __restrict__ a13,
    const float* __restrict__ a26,
    const float* __restrict__ a52,
    float* __restrict__ snoobj,     // [3][192] (167 used)
    float* __restrict__ scorr)      // [27][320] (300 used)
{
    __shared__ float sacc[27];
    __shared__ float red[8][3];

    int lane = threadIdx.x & 63;
    int wvid = threadIdx.x >> 6;

    if (blockIdx.x >= NCORR) {
        // ---------------- noobj region: 2 cells/thread, gather ch4 ----------------
        const int CT = 170352, C0 = 8112, C01 = 40560;
        int nb = blockIdx.x - NCORR;
        int i0 = nb * 1024 + threadIdx.x;
        int i1 = i0 + 512;
        // resolve both addresses first, then issue both loads (2x MLP)
        const float* q0 = nullptr; const float* q1 = nullptr;
        int sc0i = 0, sc1i = 0;
        if (i0 < CT) {
            if (i0 < C0)       { q0 = o13 + (size_t)i0 * 85 + 4;         sc0i = 0; }
            else if (i0 < C01) { q0 = o26 + (size_t)(i0 - C0) * 85 + 4;  sc0i = 1; }
            else               { q0 = o52 + (size_t)(i0 - C01) * 85 + 4; sc0i = 2; }
        }
        if (i1 < CT) {
            if (i1 < C0)       { q1 = o13 + (size_t)i1 * 85 + 4;         sc1i = 0; }
            else if (i1 < C01) { q1 = o26 + (size_t)(i1 - C0) * 85 + 4;  sc1i = 1; }
            else               { q1 = o52 + (size_t)(i1 - C01) * 85 + 4; sc1i = 2; }
        }
        float v0 = q0 ? *q0 : 0.0f;
        float v1 = q1 ? *q1 : 0.0f;
        float s[3] = { 0.0f, 0.0f, 0.0f };
        if (q0) s[sc0i] += bce0(v0);
        if (q1) s[sc1i] += bce0(v1);
        #pragma unroll
        for (int j = 0; j < 3; ++j) {
            float x = s[j];
            #pragma unroll
            for (int off = 32; off; off >>= 1) x += __shfl_down(x, off);
            if (lane == 0) red[wvid][j] = x;
        }
        __syncthreads();
        if (threadIdx.x < 3) {
            float x = 0.0f;
            #pragma unroll
            for (int w = 0; w < 8; ++w) x += red[w][threadIdx.x];
            snoobj[threadIdx.x * 192 + nb] = x;
        }
        return;
    }

    // ---------------- correct region ----------------
    if (threadIdx.x < 27) sacc[threadIdx.x] = 0.0f;
    __syncthreads();

    int wid = blockIdx.x * 8 + wvid;                // 0..2399
    int scale = wid / (NB * NT);
    int rem   = wid - scale * (NB * NT);
    int b = rem / NT, t = rem - b * NT;

    int G = (scale == 0) ? 13 : (scale == 1) ? 26 : 52;
    const float* out  = (scale == 0) ? o13 : (scale == 1) ? o26 : o52;
    const float* anch = (scale == 0) ? a13 : (scale == 1) ? a26 : a52;

    // in-register build: lane l computes target l's record
    unsigned mt = 0xFFFFFFFFu;
    float tx = 0.0f, ty = 0.0f, tw = 0.0f, th = 0.0f;
    {
        int li = (lane < NT) ? lane : NT - 1;       // clamped addr, masked below
        const float* tg = targets + ((size_t)b * NT + li) * 5;
        float4 t4 = *(const float4*)tg;             // dword-aligned, 2 loads not 5
        float x1 = t4.x, y1 = t4.y, x2 = t4.z, y2 = t4.w;
        int cls = (int)tg[4];
        float gf = (float)G;
        float bx = 0.5f * (x1 + x2) * gf;
        float by = 0.5f * (y1 + y2) * gf;
        float bw = (x2 - x1) * gf;
        float bh = (y2 - y1) * gf;
        int best = 0; float bestiou = -1.0f, aw_b = 1.0f, ah_b = 1.0f;
        unsigned nmz = 0;
        #pragma unroll
        for (int a = 0; a < NA; ++a) {
            float aw = anch[2 * a], ah = anch[2 * a + 1];
            float inter = fminf(aw, bw) * fminf(ah, bh);
            float uni = 1e-8f + aw * ah + bw * bh - inter;
            float iou = inter / uni;
            if (iou > 0.5f) nmz |= (1u << a);
            if (iou > bestiou) { bestiou = iou; best = a; aw_b = aw; ah_b = ah; }
        }
        int gi = (int)bx; gi = gi < 0 ? 0 : (gi > G - 1 ? G - 1 : gi);
        int gj = (int)by; gj = gj < 0 ? 0 : (gj > G - 1 ? G - 1 : gj);
        tx = bx - floorf(bx);
        ty = by - floorf(by);
        tw = logf(bw / aw_b);
        th = logf(bh / ah_b);
        if (lane < NT)
            mt = (unsigned)gi | ((unsigned)gj << 6) | ((unsigned)best << 12)
               | ((unsigned)cls << 14) | (nmz << 21);
    }

    unsigned key_lane = mt & 0xFFFu;
    unsigned key_t = __shfl(key_lane, t);
    int gi = key_t & 63, gj = (key_t >> 6) & 63;

    // ---- ISSUE ALL CELL LOADS IMMEDIATELY (before any ballot) ----
    const float* pc0 = out + (((size_t)(b * NA + 0) * G + gj) * G + gi) * 85;
    const float* pc1 = out + (((size_t)(b * NA + 1) * G + gj) * G + gi) * 85;
    const float* pc2 = out + (((size_t)(b * NA + 2) * G + gj) * G + gi) * 85;
    float vlo0 = pc0[lane], vlo1 = pc1[lane], vlo2 = pc2[lane];
    int hl = (lane < 21) ? 64 + lane : lane;        // valid addr; hi lanes unused
    float vhi0 = pc0[hl], vhi1 = pc1[hl], vhi2 = pc2[hl];

    // ---- ballots while loads fly ----
    unsigned long long match = __ballot(lane < NT && key_lane == key_t);
    bool canon = ((match & ((1ull << t) - 1ull)) == 0ull);   // wave-uniform

    if (canon) {
        bool mk = (lane < NT) && (key_lane == key_t);
        int bsel = (mt >> 12) & 3;
        unsigned long long bm0 = __ballot(mk && bsel == 0);
        unsigned long long bm1 = __ballot(mk && bsel == 1);
        unsigned long long bm2 = __ballot(mk && bsel == 2);
        unsigned long long nz0 = __ballot(mk && ((mt >> 21) & 1u));
        unsigned long long nz1 = __ballot(mk && ((mt >> 22) & 1u));
        unsigned long long nz2 = __ballot(mk && ((mt >> 23) & 1u));
        int myc = (mt >> 14) & 127;

        #define ANCHOR_BLOCK(A, BM, NZ, VLO, VHI)                                   \
        {                                                                           \
            bool pos = (BM) != 0ull;                                                \
            if (pos || (NZ) != 0ull) {                                              \
                if (lane == 4) {                    /* noobj correction */          \
                    atomicAdd(&sacc[scale * 9 + 5], -bce0(VLO));                    \
                    atomicAdd(&sacc[scale * 9 + 8], 1.0f);                          \
                }                                                                   \
                if (pos) {                                                          \
                    int lastt = 63 - __clzll(BM);   /* last-write-wins */           \
                    float ltx = __shfl(tx, lastt), lty = __shfl(ty, lastt);         \
                    float ltw = __shfl(tw, lastt), lth = __shfl(th, lastt);         \
                    unsigned c0, c1, c2;                                            \
                    if (__popcll(BM) == 1) {        /* single writer: 1 shfl */     \
                        int lc = __shfl(myc, lastt);                                \
                        c0 = (lc < 32) ? (1u << lc) : 0u;                           \
                        c1 = (lc >= 32 && lc < 64) ? (1u << (lc - 32)) : 0u;        \
                        c2 = (lc >= 64) ? (1u << (lc - 64)) : 0u;                   \
                    } else {                        /* rare: OR butterfly */        \
                        c0 = c1 = c2 = 0u;                                          \
                        if (((BM) >> lane) & 1ull) {                                \
                            if (myc < 32) c0 = 1u << myc;                           \
                            else if (myc < 64) c1 = 1u << (myc - 32);               \
                            else c2 = 1u << (myc - 64);                             \
                        }                                                           \
                        _Pragma("unroll")                                           \
                        for (int off = 32; off; off >>= 1) {                        \
                            c0 |= __shfl_xor(c0, off);                              \
                            c1 |= __shfl_xor(c1, off);                              \
                            c2 |= __shfl_xor(c2, off);                              \
                        }                                                           \
                    }                                                               \
                    float cls = 0.0f;                                               \
                    if (lane >= 5) {                /* channels 0..58 */            \
                        int c = lane - 5;                                           \
                        unsigned w = (c < 32) ? c0 : c1;                            \
                        cls += ((w >> (c & 31)) & 1u) ? bce1(VLO) : bce0(VLO);      \
                    }                                                               \
                    if (lane < 21) {                /* channels 59..79 */           \
                        int c = lane + 59;                                          \
                        unsigned w = (c < 64) ? c1 : c2;                            \
                        cls += ((w >> (c & 31)) & 1u) ? bce1(VHI) : bce0(VHI);      \
                    }                                                               \
                    _Pragma("unroll")                                               \
                    for (int off = 32; off; off >>= 1) cls += __shfl_xor(cls, off); \
                    if (lane == 0) {                                                \
                        atomicAdd(&sacc[scale * 9 + 6], cls);                       \
                        atomicAdd(&sacc[scale * 9 + 7], 1.0f);                      \
                    }                                                               \
                    if (lane < 4) {                 /* mse terms */                 \
                        float tv = (lane == 0) ? ltx : (lane == 1) ? lty            \
                                 : (lane == 2) ? ltw : lth;                         \
                        float d = VLO - tv;                                         \
                        atomicAdd(&sacc[scale * 9 + lane], d * d);                  \
                    }                                                               \
                    if (lane == 4) atomicAdd(&sacc[scale * 9 + 4], bce1(VLO));      \
                }                                                                   \
            }                                                                       \
        }

        ANCHOR_BLOCK(0, bm0, nz0, vlo0, vhi0)
        ANCHOR_BLOCK(1, bm1, nz1, vlo1, vhi1)
        ANCHOR_BLOCK(2, bm2, nz2, vlo2, vhi2)
        #undef ANCHOR_BLOCK
    }
    __syncthreads();
    if (threadIdx.x < 27)
        scorr[threadIdx.x * 320 + blockIdx.x] = sacc[threadIdx.x];
}

// ---------------- final: reduce slots + combine scales ----------------
__global__ __launch_bounds__(512) void final_kernel(
    const float* __restrict__ snoobj,   // [3][192]
    const float* __restrict__ scorr,    // [27][320]
    float* __restrict__ outp)
{
    float s[30];
    #pragma unroll
    for (int j = 0; j < 30; ++j) s[j] = 0.0f;
    if (threadIdx.x < NNB) {
        #pragma unroll
        for (int j = 0; j < 3; ++j) s[27 + j] += snoobj[j * 192 + threadIdx.x];
    }
    if (threadIdx.x < NCORR) {
        #pragma unroll
        for (int j = 0; j < 27; ++j) s[j] += scorr[j * 320 + threadIdx.x];
    }
    __shared__ float red[8][30];
    int lane = threadIdx.x & 63, wv = threadIdx.x >> 6;
    #pragma unroll
    for (int j = 0; j < 30; ++j) {
        float x = s[j];
        #pragma unroll
        for (int off = 32; off; off >>= 1) x += __shfl_down(x, off);
        if (lane == 0) red[wv][j] = x;
    }
    __syncthreads();
    if (threadIdx.x == 0) {
        float a[30];
        #pragma unroll
        for (int j = 0; j < 30; ++j) {
            float x = 0.0f;
            #pragma unroll
            for (int w = 0; w < 8; ++w) x += red[w][j];
            a[j] = x;
        }
        const float Stot[3] = { 8112.0f, 32448.0f, 129792.0f };
        float total = 0.0f;
        #pragma unroll
        for (int sc = 0; sc < 3; ++sc) {
            float np = a[sc * 9 + 7];
            float nn = Stot[sc] - a[sc * 9 + 8];
            float noobj = a[27 + sc] + a[sc * 9 + 5];
            total += (a[sc*9+0] + a[sc*9+1] + a[sc*9+2] + a[sc*9+3] + a[sc*9+4]) / np
                   + noobj / nn * 100.0f
                   + a[sc*9+6] / (np * (float)NC);
        }
        outp[0] = total;
    }
}

extern "C" void kernel_launch(void* const* d_in, const int* in_sizes, int n_in,
                              void* d_out, int out_size, void* d_ws, size_t ws_size,
                              hipStream_t stream)
{
    const float* out13   = (const float*)d_in[0];
    const float* out26   = (const float*)d_in[1];
    const float* out52   = (const float*)d_in[2];
    const float* targets = (const float*)d_in[3];
    const float* a13     = (const float*)d_in[4];
    const float* a26     = (const float*)d_in[5];
    const float* a52     = (const float*)d_in[6];

    // ws: snoobj[3][192] at 0 (2304 B); scorr[27][320] at 4096 (34560 B)
    float* snoobj = (float*)d_ws;
    float* scorr  = (float*)((char*)d_ws + 4096);

    main_kernel<<<NBLK, 512, 0, stream>>>(
        out13, out26, out52, targets, a13, a26, a52, snoobj, scorr);

    final_kernel<<<1, 512, 0, stream>>>(snoobj, scorr, (float*)d_out);
}